// Round 13
// baseline (685.757 us; speedup 1.0000x reference)
//
#include <hip/hip_runtime.h>
#include <hip/hip_bf16.h>

typedef unsigned int u32;
typedef unsigned short u16;
typedef unsigned long long u64;

using bf16x8 = __attribute__((ext_vector_type(8))) short;
using f32x4  = __attribute__((ext_vector_type(4))) float;
typedef float f4v __attribute__((ext_vector_type(4)));

#define NUNITS 31
#define WS_BIAS_OFF (NUNITS*8192)
#define NBIAS 1952
#define SCL2 0.25503512f     // 1/sqrt(32) * log2(e)
#define L2E  1.4426950408889634f

__device__ __forceinline__ u32 pk2(float a, float b){
    __hip_bfloat162 h = __float22bfloat162_rn(make_float2(a, b));
    union { __hip_bfloat162 h2; u32 u; } cv; cv.h2 = h; return cv.u;
}
__device__ __forceinline__ float b2f(u16 v){ return __uint_as_float(((u32)v) << 16); }
__device__ __forceinline__ int swch(int chunk, int key){ return (chunk & ~7) | ((chunk ^ key) & 7); }
__device__ __forceinline__ float sigx(float v){
    return __builtin_amdgcn_rcpf(1.f + __builtin_amdgcn_exp2f(-L2E * v));
}

// ---------------- weight pre-conversion (identical layout to R7-R12) ----------------
__global__ __launch_bounds__(256) void convert_weights(
    const float* __restrict__ enc_w,
    const float* __restrict__ q1, const float* __restrict__ k1,
    const float* __restrict__ v1, const float* __restrict__ o1,
    const float* __restrict__ q2, const float* __restrict__ k2,
    const float* __restrict__ v2, const float* __restrict__ o2,
    const float* __restrict__ gih, const float* __restrict__ ghh,
    const float* __restrict__ lin,
    const float* __restrict__ enc_b,
    const float* __restrict__ q1b, const float* __restrict__ k1b,
    const float* __restrict__ v1b, const float* __restrict__ o1b,
    const float* __restrict__ q2b, const float* __restrict__ k2b,
    const float* __restrict__ v2b, const float* __restrict__ o2b,
    const float* __restrict__ gbih, const float* __restrict__ gbhh,
    const float* __restrict__ linb,
    u16* __restrict__ dst)
{
    int idx = blockIdx.x*256 + threadIdx.x;
    if (idx < NUNITS*8192){
        int u = idx >> 13, rem = idx & 8191;
        int w = rem >> 11;
        int t = (rem >> 9) & 3;
        int l = (rem >> 3) & 63;
        int e = idx & 7;
        int i = t >> 1, kk = t & 1;
        int oc = (w*2 + i)*16 + (l & 15);
        int kl = kk*32 + (l >> 4)*8 + e;
        float val;
        if (u == 0){
            val = enc_w[oc*64 + kl];
        } else if (u <= 16){
            int v = u - 1; int L = v >> 3; int r8 = v & 7;
            int mat, kh;
            if (r8 < 6){ mat = r8 % 3; kh = r8 / 3; } else { mat = 3; kh = r8 - 6; }
            const float* s;
            if (L == 0){ s = (mat==0)?q1:(mat==1)?k1:(mat==2)?v1:o1; }
            else       { s = (mat==0)?q2:(mat==1)?k2:(mat==2)?v2:o2; }
            val = s[oc*128 + kh*64 + kl];
        } else if (u <= 28){
            int v = u - 17;
            int gate, kh; const float* s;
            if (v < 8){ gate = v & 1; kh = (v >> 1) & 1; s = (v >= 4) ? ghh : gih; }
            else      { int w8 = v - 8; gate = 2; kh = w8 & 1; s = (w8 >= 2) ? ghh : gih; }
            val = s[(gate*128 + oc)*128 + kh*64 + kl];
        } else {
            int kh = u - 29;
            val = (oc < 20) ? lin[oc*128 + kh*64 + kl] : 0.f;
        }
        __hip_bfloat16 hv = __float2bfloat16(val);
        union { __hip_bfloat16 h; u16 us; } cv; cv.h = hv;
        dst[idx] = cv.us;
    } else if (idx < NUNITS*8192 + NBIAS){
        int i = idx - NUNITS*8192;
        float val;
        if      (i < 128)  val = enc_b[i];
        else if (i < 256)  val = q1b[i-128];
        else if (i < 384)  val = k1b[i-256];
        else if (i < 512)  val = v1b[i-384];
        else if (i < 640)  val = o1b[i-512];
        else if (i < 768)  val = q2b[i-640];
        else if (i < 896)  val = k2b[i-768];
        else if (i < 1024) val = v2b[i-896];
        else if (i < 1152) val = o2b[i-1024];
        else if (i < 1536) val = gbih[i-1152];
        else if (i < 1920) val = gbhh[i-1536];
        else if (i < 1940) val = linb[i-1920];
        else               val = 0.f;
        ((float*)(dst + NUNITS*8192))[i] = val;
    }
}

// ---------------- primitives ----------------
#define BARX() do{ asm volatile("s_waitcnt lgkmcnt(0)" ::: "memory"); \
                   __builtin_amdgcn_s_barrier(); \
                   asm volatile("" ::: "memory"); }while(0)

struct WB { bf16x8 a[4]; };   // a[i*2+kk]

template<int U>
__device__ __forceinline__ WB load_unit(const u16* Wu, int w, int lane){
    const u16* p = Wu + U*8192 + w*2048 + lane*8;
    WB b;
    b.a[0] = *(const bf16x8*)(p);
    b.a[1] = *(const bf16x8*)(p + 512);
    b.a[2] = *(const bf16x8*)(p + 1024);
    b.a[3] = *(const bf16x8*)(p + 1536);
    return b;
}

#define Z4 ((f32x4){0.f,0.f,0.f,0.f})
#define MFMA(a,b,c) __builtin_amdgcn_mfma_f32_16x16x32_bf16((a),(b),(c),0,0,0)

struct XF { bf16x8 f[4][2]; };

__device__ __forceinline__ void loadX(XF& xf, const u16* X, int kh, int c, int g){
    const int key = c & 7;
    #pragma unroll
    for (int kk = 0; kk < 2; kk++){
        const int pw = (kk*4 + g) ^ key;
        #pragma unroll
        for (int j = 0; j < 4; j++)
            xf.f[j][kk] = *(const bf16x8*)(X + (j*16 + c)*128 + (kh*8 + pw)*8);
    }
}

template<bool FIRST>
__device__ __forceinline__ void wgemmW(const WB& wb, const XF& xf, f32x4 (&acc)[2][4]){
    __builtin_amdgcn_s_setprio(1);
    #pragma unroll
    for (int j = 0; j < 4; j++){
        acc[0][j] = FIRST ? MFMA(wb.a[0], xf.f[j][0], Z4) : MFMA(wb.a[0], xf.f[j][0], acc[0][j]);
        acc[1][j] = FIRST ? MFMA(wb.a[2], xf.f[j][0], Z4) : MFMA(wb.a[2], xf.f[j][0], acc[1][j]);
    }
    #pragma unroll
    for (int j = 0; j < 4; j++){
        acc[0][j] = MFMA(wb.a[1], xf.f[j][1], acc[0][j]);
        acc[1][j] = MFMA(wb.a[3], xf.f[j][1], acc[1][j]);
    }
    __builtin_amdgcn_s_setprio(0);
}

template<bool FIRST>
__device__ __forceinline__ void vgemmW(const WB& wb, const XF& xf, f32x4 (&acc)[4][2]){
    __builtin_amdgcn_s_setprio(1);
    #pragma unroll
    for (int i = 0; i < 4; i++){
        acc[i][0] = FIRST ? MFMA(xf.f[i][0], wb.a[0], Z4) : MFMA(xf.f[i][0], wb.a[0], acc[i][0]);
        acc[i][1] = FIRST ? MFMA(xf.f[i][0], wb.a[2], Z4) : MFMA(xf.f[i][0], wb.a[2], acc[i][1]);
    }
    #pragma unroll
    for (int i = 0; i < 4; i++){
        acc[i][0] = MFMA(xf.f[i][1], wb.a[1], acc[i][0]);
        acc[i][1] = MFMA(xf.f[i][1], wb.a[3], acc[i][1]);
    }
    __builtin_amdgcn_s_setprio(0);
}

template<bool QS>
__device__ __forceinline__ void epiW(f32x4 (&acc)[2][4], float4 bv0, float4 bv1,
                                     u16* dst, int w, int c, int g){
    const int key = c & 7;
    #pragma unroll
    for (int i = 0; i < 2; i++){
        float4 bv = i ? bv1 : bv0;
        const int col0 = (w*2+i)*16 + g*4;
        const int coff = swch(col0>>3, key)*8 + (col0&7);
        #pragma unroll
        for (int j = 0; j < 4; j++){
            int row = j*16 + c;
            float v0 = fmaxf(acc[i][j][0]+bv.x, 0.f);
            float v1 = fmaxf(acc[i][j][1]+bv.y, 0.f);
            float v2 = fmaxf(acc[i][j][2]+bv.z, 0.f);
            float v3 = fmaxf(acc[i][j][3]+bv.w, 0.f);
            if (QS){ v0 *= SCL2; v1 *= SCL2; v2 *= SCL2; v3 *= SCL2; }
            uint2 o; o.x = pk2(v0,v1); o.y = pk2(v2,v3);
            *(uint2*)(dst + row*128 + coff) = o;
        }
    }
}

// ---------------- one MHA layer: R8 schedule on 2-buffer ping-pong ----------------
// entry: IN = layer input (visible); OUT = dead.
// exit : OUT = layer output (visible); IN = dead (L1: h0-bf16).
template<int LAYER>
__device__ __forceinline__ void mha_layer(const u16* Wu,
                                          u16* IN, u16* OUT,
                                          const float* wsb, const float* h0, size_t rowbase,
                                          int tid, int w, int lane, int c, int g, const u64* mbits,
                                          WB b_q0, WB b_k0, WB b_v0,
                                          WB& nx0, WB& nx1, WB& nx2)
{
    constexpr int UB = 1 + LAYER*8;
    constexpr int BB = 128 + LAYER*512;
    const int key = c & 7;
    const int col00 = w*32 + g*4;
    const int col01 = col00 + 16;
    const int h = w;

    XF xf;
    f32x4 accQ[2][4], accK[2][4];
    f32x4 vacc[4][2];

    loadX(xf, IN, 0, c, g);
    wgemmW<true>(b_q0, xf, accQ);
    WB b_q1 = load_unit<UB+3>(Wu, w, lane);
    wgemmW<true>(b_k0, xf, accK);
    WB b_k1 = load_unit<UB+4>(Wu, w, lane);
    vgemmW<true>(b_v0, xf, vacc);
    WB b_v1 = load_unit<UB+5>(Wu, w, lane);

    loadX(xf, IN, 1, c, g);
    float4 bq0 = *(const float4*)(wsb + BB + col00);
    float4 bq1 = *(const float4*)(wsb + BB + col01);
    wgemmW<false>(b_q1, xf, accQ);
    WB b_o0 = load_unit<UB+6>(Wu, w, lane);
    epiW<true>(accQ, bq0, bq1, OUT, w, c, g);     // Q (exp2-scaled) -> OUT (dead)

    float4 bk0 = *(const float4*)(wsb + BB + 128 + col00);
    float4 bk1 = *(const float4*)(wsb + BB + 128 + col01);
    wgemmW<false>(b_k1, xf, accK);
    WB b_o1 = load_unit<UB+7>(Wu, w, lane);

    float bv0 = wsb[BB + 256 + w*32 + c];
    float bv1 = wsb[BB + 256 + w*32 + 16 + c];
    vgemmW<false>(b_v1, xf, vacc);

    BARX();   // barrier1: all waves' IN reads done -> K may overwrite IN

    epiW<false>(accK, bk0, bk1, IN, w, c, g);     // K -> IN (wave-private cols)

    // scores: mfma(K, Qs) — wave-private columns (h = w)
    f32x4 sc[4][4];
    {
        bf16x8 kf[4];
        #pragma unroll
        for (int kt = 0; kt < 4; kt++)
            kf[kt] = *(const bf16x8*)(IN + (kt*16 + c)*128 + swch(h*4+g, key)*8);
        __builtin_amdgcn_s_setprio(1);
        #pragma unroll
        for (int qt = 0; qt < 4; qt++){
            bf16x8 qf = *(const bf16x8*)(OUT + (qt*16 + c)*128 + swch(h*4+g, key)*8);
            #pragma unroll
            for (int kt = 0; kt < 4; kt++)
                sc[qt][kt] = MFMA(kf[kt], qf, Z4);
        }
        __builtin_amdgcn_s_setprio(0);
    }

    // T14 issue-early: h0 loads during softmax (LAYER 1)
    f4v hr[8];
    if (LAYER == 1){
        const float* hp = h0 + (rowbase + (tid>>2))*128 + (tid&3)*32;
        #pragma unroll
        for (int t = 0; t < 8; t++)
            hr[t] = __builtin_nontemporal_load((const f4v*)(hp + t*4));
    }

    u32 pp[4][4][2];
    float inv[4];
    #pragma unroll
    for (int qt = 0; qt < 4; qt++){
        u64 mb = mbits[qt];
        float sum = 0.f;
        #pragma unroll
        for (int kt = 0; kt < 4; kt++)
            #pragma unroll
            for (int r = 0; r < 4; r++){
                float s = ((mb >> (kt*16 + g*4 + r)) & 1ull) ? sc[qt][kt][r] : -1e30f;
                float e = __builtin_amdgcn_exp2f(s);
                sc[qt][kt][r] = e; sum += e;
            }
        sum += __shfl_xor(sum, 16);
        sum += __shfl_xor(sum, 32);
        inv[qt] = __builtin_amdgcn_rcpf(sum);
        #pragma unroll
        for (int kt = 0; kt < 4; kt++){
            pp[qt][kt][0] = pk2(sc[qt][kt][0], sc[qt][kt][1]);
            pp[qt][kt][1] = pk2(sc[qt][kt][2], sc[qt][kt][3]);
        }
    }

    BARX();   // barrier2: all waves' Q/K reads done -> Q dead (OUT), K dead (IN)

    // V^T -> OUT (own rows)
    #pragma unroll
    for (int j = 0; j < 2; j++){
        int vrow = w*32 + j*16 + c;
        float bv = j ? bv1 : bv0;
        #pragma unroll
        for (int i = 0; i < 4; i++){
            int kk = i >> 1, p = i & 1;
            float v0 = fmaxf(vacc[i][j][0]+bv, 0.f);
            float v1 = fmaxf(vacc[i][j][1]+bv, 0.f);
            float v2 = fmaxf(vacc[i][j][2]+bv, 0.f);
            float v3 = fmaxf(vacc[i][j][3]+bv, 0.f);
            uint2 o; o.x = pk2(v0,v1); o.y = pk2(v2,v3);
            *(uint2*)(OUT + vrow*64 + swch(kk*4+g, key)*8 + p*4) = o;
        }
    }

    // PV (own V^T slab) -> X1 into IN (own cols)
    #pragma unroll
    for (int dt = 0; dt < 2; dt++){
        f32x4 pa[4];
        #pragma unroll
        for (int kk = 0; kk < 2; kk++){
            bf16x8 vt = *(const bf16x8*)(OUT + (h*32 + dt*16 + c)*64 + ((kk*4+g)^key)*8);
            __builtin_amdgcn_s_setprio(1);
            #pragma unroll
            for (int qt = 0; qt < 4; qt++){
                union { u32 u4[4]; bf16x8 v8; } bbv;
                bbv.u4[0]=pp[qt][kk*2][0];   bbv.u4[1]=pp[qt][kk*2][1];
                bbv.u4[2]=pp[qt][kk*2+1][0]; bbv.u4[3]=pp[qt][kk*2+1][1];
                pa[qt] = (kk == 0) ? MFMA(vt, bbv.v8, Z4) : MFMA(vt, bbv.v8, pa[qt]);
            }
            __builtin_amdgcn_s_setprio(0);
        }
        #pragma unroll
        for (int qt = 0; qt < 4; qt++){
            int col = h*32 + dt*16 + g*4;
            float iv = inv[qt];
            uint2 o; o.x = pk2(pa[qt][0]*iv, pa[qt][1]*iv); o.y = pk2(pa[qt][2]*iv, pa[qt][3]*iv);
            *(uint2*)(IN + (qt*16 + c)*128 + swch(col>>3, key)*8 + (col&7)) = o;
        }
    }

    BARX();   // barrier3: all X1 writes visible

    // O-projection from IN(X1) -> OUT
    f32x4 acc[2][4];
    loadX(xf, IN, 0, c, g);
    wgemmW<true>(b_o0, xf, acc);
    loadX(xf, IN, 1, c, g);

    if (LAYER == 1){
        BARX();   // barrier3.5: all waves' X1 reads done -> IN free for h0
        int hrow = tid >> 2, seg = tid & 3;
        #pragma unroll
        for (int cc = 0; cc < 4; cc++){
            int p = seg*4 + cc;
            int ps = (p & 8) | ((p ^ (hrow & 7)) & 7);
            f4v fa = hr[cc*2], fb = hr[cc*2+1];
            uint4 o; o.x = pk2(fa.x,fa.y); o.y = pk2(fa.z,fa.w);
            o.z = pk2(fb.x,fb.y); o.w = pk2(fb.z,fb.w);
            *(uint4*)(IN + hrow*128 + ps*8) = o;
        }
    }

    float4 bo0 = *(const float4*)(wsb + BB + 384 + col00);
    float4 bo1 = *(const float4*)(wsb + BB + 384 + col01);
    wgemmW<false>(b_o1, xf, acc);
    nx0 = load_unit<UB+8>(Wu, w, lane);
    nx1 = load_unit<UB+9>(Wu, w, lane);
    nx2 = load_unit<UB+10>(Wu, w, lane);
    epiW<false>(acc, bo0, bo1, OUT, w, c, g);

    BARX();   // barrier4: OUT (layer result) + h0 (L1) visible
}

// ---------------- main fused kernel: 1 batch item / block, 256 threads, min 3 waves/EU ----------------
__global__ __launch_bounds__(256, 3) void drgn_pipe(
    const float* __restrict__ x, const int* __restrict__ maskg,
    const float* __restrict__ h0, const u16* __restrict__ W16,
    float* __restrict__ out_qs, float* __restrict__ out_h3)
{
    __shared__ __align__(16) u16 SMEM[16384];   // 32768 B: 2 x [64][128] bf16
    u16* A = SMEM;
    u16* B = SMEM + 8192;

    const int tid = threadIdx.x;
    const int w = tid >> 6, lane = tid & 63;
    const int c = lane & 15, g = lane >> 4;
    const int key = c & 7;
    const size_t rowbase = (size_t)blockIdx.x * 64;
    const u16* Wu = W16;
    const float* wsb = (const float*)(W16 + WS_BIAS_OFF);
    const int col00 = w*32 + g*4;
    const int col01 = col00 + 16;

    // ---- prologue: mask bits -> regs (via B transient), x -> A bf16 ----
    u64* MrowT = (u64*)B;
    #pragma unroll 4
    for (int rr = 0; rr < 16; rr++){
        int row = w*16 + rr;
        int mv = __builtin_nontemporal_load(maskg + (rowbase + row)*64 + lane);
        u64 bits = __ballot(mv != 0);
        if (lane == 0) MrowT[row] = bits;
    }
    for (int i = tid; i < 512; i += 256){
        int row = i >> 3, p = i & 7;
        int lc = (p ^ (row & 7)) & 7;
        const float* sp = x + (rowbase + row)*64 + lc*8;
        f4v f0 = __builtin_nontemporal_load((const f4v*)sp);
        f4v f1 = __builtin_nontemporal_load((const f4v*)(sp + 4));
        uint4 o; o.x = pk2(f0.x,f0.y); o.y = pk2(f0.z,f0.w);
        o.z = pk2(f1.x,f1.y); o.w = pk2(f1.z,f1.w);
        *(uint4*)(A + row*128 + p*8) = o;
    }
    WB b_enc = load_unit<0>(Wu, w, lane);
    WB n0 = load_unit<1>(Wu, w, lane);
    WB n1 = load_unit<2>(Wu, w, lane);
    WB n2 = load_unit<3>(Wu, w, lane);
    __syncthreads();
    u64 mbits[4];
    #pragma unroll
    for (int qt = 0; qt < 4; qt++) mbits[qt] = MrowT[qt*16 + c];

    // ---- encoder (unit 0): B = relu(x @ enc^T + b) ----
    {
        XF xf;
        f32x4 acc[2][4];
        float4 b0 = *(const float4*)(wsb + col00);
        float4 b1 = *(const float4*)(wsb + col01);
        loadX(xf, A, 0, c, g);
        wgemmW<true>(b_enc, xf, acc);
        BARX();   // all mbits reads + A(x) reads done -> B overwrite safe
        epiW<false>(acc, b0, b1, B, w, c, g);
    }
    BARX();       // enc-out visible; A dead

    // ---- two MHA layers (ping-pong) ----
    mha_layer<0>(Wu, B, A, wsb, h0, rowbase, tid, w, lane, c, g, mbits,
                 n0, n1, n2, n0, n1, n2);
    mha_layer<1>(Wu, A, B, wsb, h0, rowbase, tid, w, lane, c, g, mbits,
                 n0, n1, n2, n0, n1, n2);   // exit: B = h2, A = h0(bf16); n = g17,18,19

    // ---- GRU: h2 = B, h0 = A ----
    XF xf;
    float rrA[2][4][4], zzA[2][4][4];
    WB g29, g30;
    {
        f32x4 aIr[2][4], aIz[2][4], aHr[2][4], aHz[2][4];
        loadX(xf, B, 0, c, g);
        wgemmW<true>(n0, xf, aIr);                       // r_ih0
        WB g20 = load_unit<20>(Wu, w, lane);
        wgemmW<true>(n1, xf, aIz);                       // z_ih0
        WB g21 = load_unit<21>(Wu, w, lane);
        loadX(xf, B, 1, c, g);
        wgemmW<false>(n2, xf, aIr);                      // r_ih1
        WB g22 = load_unit<22>(Wu, w, lane);
        wgemmW<false>(g20, xf, aIz);                     // z_ih1
        WB g23 = load_unit<23>(Wu, w, lane);
        loadX(xf, A, 0, c, g);
        wgemmW<true>(g21, xf, aHr);                      // r_hh0
        WB g24 = load_unit<24>(Wu, w, lane);
        wgemmW<true>(g22, xf, aHz);                      // z_hh0
        WB g25 = load_unit<25>(Wu, w, lane);
        loadX(xf, A, 1, c, g);
        wgemmW<false>(g23, xf, aHr);                     // r_hh1
        WB g26 = load_unit<26>(Wu, w, lane);
        wgemmW<false>(g24, xf, aHz);                     // z_hh1
        WB g27 = load_unit<27>(Wu, w, lane);

        float4 bir0 = *(const float4*)(wsb + 1152 + col00);
        float4 bir1 = *(const float4*)(wsb + 1152 + col01);
        float4 bhr0 = *(const float4*)(wsb + 1536 + col00);
        float4 bhr1 = *(const float4*)(wsb + 1536 + col01);
        float4 biz0 = *(const float4*)(wsb + 1152 + 128 + col00);
        float4 biz1 = *(const float4*)(wsb + 1152 + 128 + col01);
        float4 bhz0 = *(const float4*)(wsb + 1536 + 128 + col00);
        float4 bhz1 = *(const float4*)(wsb + 1536 + 128 + col01);
        #pragma unroll
        for (int i = 0; i < 2; i++){
            float4 bir = i ? bir1 : bir0; float4 bhr = i ? bhr1 : bhr0;
            float4 biz = i ? biz1 : biz0; float4 bhz = i ? bhz1 : bhz0;
            #pragma unroll
            for (int j = 0; j < 4; j++)
                #pragma unroll
                for (int r = 0; r < 4; r++){
                    rrA[i][j][r] = sigx(aIr[i][j][r] + (&bir.x)[r] + aHr[i][j][r] + (&bhr.x)[r]);
                    zzA[i][j][r] = sigx(aIz[i][j][r] + (&biz.x)[r] + aHz[i][j][r] + (&bhz.x)[r]);
                }
        }

        // n gate
        f32x4 aIn[2][4], aHn[2][4];
        loadX(xf, B, 0, c, g);
        wgemmW<true>(g25, xf, aIn);
        WB g28 = load_unit<28>(Wu, w, lane);
        loadX(xf, B, 1, c, g);
        wgemmW<false>(g26, xf, aIn);
        g29 = load_unit<29>(Wu, w, lane);
        loadX(xf, A, 0, c, g);
        wgemmW<true>(g27, xf, aHn);
        g30 = load_unit<30>(Wu, w, lane);
        loadX(xf, A, 1, c, g);
        wgemmW<false>(g28, xf, aHn);

        float4 bin0 = *(const float4*)(wsb + 1152 + 256 + col00);
        float4 bin1 = *(const float4*)(wsb + 1152 + 256 + col01);
        float4 bhn0 = *(const float4*)(wsb + 1536 + 256 + col00);
        float4 bhn1 = *(const float4*)(wsb + 1536 + 256 + col01);

        BARX();   // all waves' B/A reads done -> h3 may overwrite B

        #pragma unroll
        for (int i = 0; i < 2; i++){
            float4 bi = i ? bin1 : bin0; float4 bh = i ? bhn1 : bhn0;
            int col0 = w*32 + i*16 + g*4;
            int coff = swch(col0>>3, key)*8 + (col0&7);
            #pragma unroll
            for (int j = 0; j < 4; j++){
                int row = j*16 + c;
                uint2 hv = *(const uint2*)(A + row*128 + coff);
                float h0v[4] = { b2f((u16)(hv.x & 0xffffu)), b2f((u16)(hv.x >> 16)),
                                 b2f((u16)(hv.y & 0xffffu)), b2f((u16)(hv.y >> 16)) };
                f4v h3o;
                #pragma unroll
                for (int r = 0; r < 4; r++){
                    float xn = aIn[i][j][r] + (&bi.x)[r] + rrA[i][j][r]*(aHn[i][j][r] + (&bh.x)[r]);
                    float e2 = __builtin_amdgcn_exp2f(-2.f*L2E*fabsf(xn));
                    float th = (1.f - e2)*__builtin_amdgcn_rcpf(1.f + e2);
                    th = (xn >= 0.f) ? th : -th;
                    float zv = zzA[i][j][r];
                    h3o[r] = (1.f - zv)*th + zv*h0v[r];
                }
                uint2 o; o.x = pk2(h3o[0],h3o[1]); o.y = pk2(h3o[2],h3o[3]);
                *(uint2*)(B + row*128 + coff) = o;   // h3 bf16 -> B (for qs GEMM)
                __builtin_nontemporal_store(h3o, (f4v*)(out_h3 + (rowbase + row)*128 + col0));
            }
        }
    }
    BARX();   // h3 visible

    // ---- final linear (units 29,30) + qs stores ----
    {
        f32x4 qa[2][4];
        float4 lb0 = (col00 < 20) ? *(const float4*)(wsb + 1920 + col00) : (float4){0.f,0.f,0.f,0.f};
        float4 lb1 = (col01 < 20) ? *(const float4*)(wsb + 1920 + col01) : (float4){0.f,0.f,0.f,0.f};
        loadX(xf, B, 0, c, g);
        wgemmW<true>(g29, xf, qa);
        loadX(xf, B, 1, c, g);
        wgemmW<false>(g30, xf, qa);

        #pragma unroll
        for (int i = 0; i < 2; i++){
            int col0 = w*32 + i*16 + g*4;
            if (col0 < 20){
                float4 lb = i ? lb1 : lb0;
                #pragma unroll
                for (int j = 0; j < 4; j++){
                    int row = j*16 + c;
                    f4v o;
                    o.x = qa[i][j][0]+lb.x; o.y = qa[i][j][1]+lb.y;
                    o.z = qa[i][j][2]+lb.z; o.w = qa[i][j][3]+lb.w;
                    __builtin_nontemporal_store(o, (f4v*)(out_qs + (rowbase + row)*20 + col0));
                }
            }
        }
    }
}

extern "C" void kernel_launch(void* const* d_in, const int* in_sizes, int n_in,
                              void* d_out, int out_size, void* d_ws, size_t ws_size,
                              hipStream_t stream) {
    const float* x     = (const float*)d_in[0];
    const int*   mask  = (const int*)  d_in[1];
    const float* h0    = (const float*)d_in[2];
    const float* enc_w = (const float*)d_in[3];
    const float* enc_b = (const float*)d_in[4];
    const float* q1_w  = (const float*)d_in[5];  const float* q1_b = (const float*)d_in[6];
    const float* k1_w  = (const float*)d_in[7];  const float* k1_b = (const float*)d_in[8];
    const float* v1_w  = (const float*)d_in[9];  const float* v1_b = (const float*)d_in[10];
    const float* o1_w  = (const float*)d_in[11]; const float* o1_b = (const float*)d_in[12];
    const float* q2_w  = (const float*)d_in[13]; const float* q2_b = (const float*)d_in[14];
    const float* k2_w  = (const float*)d_in[15]; const float* k2_b = (const float*)d_in[16];
    const float* v2_w  = (const float*)d_in[17]; const float* v2_b = (const float*)d_in[18];
    const float* o2_w  = (const float*)d_in[19]; const float* o2_b = (const float*)d_in[20];
    const float* gwih  = (const float*)d_in[21]; const float* gwhh = (const float*)d_in[22];
    const float* gbih  = (const float*)d_in[23]; const float* gbhh = (const float*)d_in[24];
    const float* lin_w = (const float*)d_in[25]; const float* lin_b = (const float*)d_in[26];

    const int bs = in_sizes[0] / (64 * 64);           // 4096
    float* out_qs = (float*)d_out;
    float* out_h3 = out_qs + (size_t)bs * 64 * 20;
    u16* W16 = (u16*)d_ws;

    const int total = NUNITS*8192 + NBIAS;
    hipLaunchKernelGGL(convert_weights, dim3((total + 255) / 256), dim3(256), 0, stream,
                       enc_w, q1_w, k1_w, v1_w, o1_w, q2_w, k2_w, v2_w, o2_w,
                       gwih, gwhh, lin_w,
                       enc_b, q1_b, k1_b, v1_b, o1_b, q2_b, k2_b, v2_b, o2_b,
                       gbih, gbhh, lin_b, W16);
    hipLaunchKernelGGL(drgn_pipe, dim3(bs), dim3(256), 0, stream,
                       x, mask, h0, W16, out_qs, out_h3);
}

// Round 14
// 585.356 us; speedup vs baseline: 1.1715x; 1.1715x over previous
//
#include <hip/hip_runtime.h>
#include <hip/hip_bf16.h>

typedef unsigned int u32;
typedef unsigned short u16;
typedef unsigned long long u64;

using bf16x8 = __attribute__((ext_vector_type(8))) short;
using f32x4  = __attribute__((ext_vector_type(4))) float;
typedef float f4v __attribute__((ext_vector_type(4)));

#define NUNITS 31
#define WS_BIAS_OFF (NUNITS*8192)
#define NBIAS 1952
#define SCL2 0.25503512f     // 1/sqrt(32) * log2(e)
#define L2E  1.4426950408889634f

__device__ __forceinline__ u32 pk2(float a, float b){
    __hip_bfloat162 h = __float22bfloat162_rn(make_float2(a, b));
    union { __hip_bfloat162 h2; u32 u; } cv; cv.h2 = h; return cv.u;
}
__device__ __forceinline__ float b2f(u16 v){ return __uint_as_float(((u32)v) << 16); }
__device__ __forceinline__ int swch(int chunk, int key){ return (chunk & ~7) | ((chunk ^ key) & 7); }
__device__ __forceinline__ float sigx(float v){
    return __builtin_amdgcn_rcpf(1.f + __builtin_amdgcn_exp2f(-L2E * v));
}

// ---------------- weight pre-conversion (identical layout to R7-R13) ----------------
__global__ __launch_bounds__(256) void convert_weights(
    const float* __restrict__ enc_w,
    const float* __restrict__ q1, const float* __restrict__ k1,
    const float* __restrict__ v1, const float* __restrict__ o1,
    const float* __restrict__ q2, const float* __restrict__ k2,
    const float* __restrict__ v2, const float* __restrict__ o2,
    const float* __restrict__ gih, const float* __restrict__ ghh,
    const float* __restrict__ lin,
    const float* __restrict__ enc_b,
    const float* __restrict__ q1b, const float* __restrict__ k1b,
    const float* __restrict__ v1b, const float* __restrict__ o1b,
    const float* __restrict__ q2b, const float* __restrict__ k2b,
    const float* __restrict__ v2b, const float* __restrict__ o2b,
    const float* __restrict__ gbih, const float* __restrict__ gbhh,
    const float* __restrict__ linb,
    u16* __restrict__ dst)
{
    int idx = blockIdx.x*256 + threadIdx.x;
    if (idx < NUNITS*8192){
        int u = idx >> 13, rem = idx & 8191;
        int w = rem >> 11;
        int t = (rem >> 9) & 3;
        int l = (rem >> 3) & 63;
        int e = idx & 7;
        int i = t >> 1, kk = t & 1;
        int oc = (w*2 + i)*16 + (l & 15);
        int kl = kk*32 + (l >> 4)*8 + e;
        float val;
        if (u == 0){
            val = enc_w[oc*64 + kl];
        } else if (u <= 16){
            int v = u - 1; int L = v >> 3; int r8 = v & 7;
            int mat, kh;
            if (r8 < 6){ mat = r8 % 3; kh = r8 / 3; } else { mat = 3; kh = r8 - 6; }
            const float* s;
            if (L == 0){ s = (mat==0)?q1:(mat==1)?k1:(mat==2)?v1:o1; }
            else       { s = (mat==0)?q2:(mat==1)?k2:(mat==2)?v2:o2; }
            val = s[oc*128 + kh*64 + kl];
        } else if (u <= 28){
            int v = u - 17;
            int gate, kh; const float* s;
            if (v < 8){ gate = v & 1; kh = (v >> 1) & 1; s = (v >= 4) ? ghh : gih; }
            else      { int w8 = v - 8; gate = 2; kh = w8 & 1; s = (w8 >= 2) ? ghh : gih; }
            val = s[(gate*128 + oc)*128 + kh*64 + kl];
        } else {
            int kh = u - 29;
            val = (oc < 20) ? lin[oc*128 + kh*64 + kl] : 0.f;
        }
        __hip_bfloat16 hv = __float2bfloat16(val);
        union { __hip_bfloat16 h; u16 us; } cv; cv.h = hv;
        dst[idx] = cv.us;
    } else if (idx < NUNITS*8192 + NBIAS){
        int i = idx - NUNITS*8192;
        float val;
        if      (i < 128)  val = enc_b[i];
        else if (i < 256)  val = q1b[i-128];
        else if (i < 384)  val = k1b[i-256];
        else if (i < 512)  val = v1b[i-384];
        else if (i < 640)  val = o1b[i-512];
        else if (i < 768)  val = q2b[i-640];
        else if (i < 896)  val = k2b[i-768];
        else if (i < 1024) val = v2b[i-896];
        else if (i < 1152) val = o2b[i-1024];
        else if (i < 1536) val = gbih[i-1152];
        else if (i < 1920) val = gbhh[i-1536];
        else if (i < 1940) val = linb[i-1920];
        else               val = 0.f;
        ((float*)(dst + NUNITS*8192))[i] = val;
    }
}

// ---------------- primitives ----------------
#define BARX() do{ asm volatile("s_waitcnt lgkmcnt(0)" ::: "memory"); \
                   __builtin_amdgcn_s_barrier(); \
                   asm volatile("" ::: "memory"); }while(0)

struct WB { bf16x8 a[4]; };   // a[i*2+kk]

template<int U>
__device__ __forceinline__ WB load_unit(const u16* Wu, int w, int lane){
    const u16* p = Wu + U*8192 + w*2048 + lane*8;
    WB b;
    b.a[0] = *(const bf16x8*)(p);
    b.a[1] = *(const bf16x8*)(p + 512);
    b.a[2] = *(const bf16x8*)(p + 1024);
    b.a[3] = *(const bf16x8*)(p + 1536);
    return b;
}

#define Z4 ((f32x4){0.f,0.f,0.f,0.f})
#define MFMA(a,b,c) __builtin_amdgcn_mfma_f32_16x16x32_bf16((a),(b),(c),0,0,0)

struct XF { bf16x8 f[4][2]; };

__device__ __forceinline__ void loadX(XF& xf, const u16* X, int kh, int c, int g){
    const int key = c & 7;
    #pragma unroll
    for (int kk = 0; kk < 2; kk++){
        const int pw = (kk*4 + g) ^ key;
        #pragma unroll
        for (int j = 0; j < 4; j++)
            xf.f[j][kk] = *(const bf16x8*)(X + (j*16 + c)*128 + (kh*8 + pw)*8);
    }
}

template<bool FIRST>
__device__ __forceinline__ void wgemmW(const WB& wb, const XF& xf, f32x4 (&acc)[2][4]){
    __builtin_amdgcn_s_setprio(1);
    #pragma unroll
    for (int j = 0; j < 4; j++){
        acc[0][j] = FIRST ? MFMA(wb.a[0], xf.f[j][0], Z4) : MFMA(wb.a[0], xf.f[j][0], acc[0][j]);
        acc[1][j] = FIRST ? MFMA(wb.a[2], xf.f[j][0], Z4) : MFMA(wb.a[2], xf.f[j][0], acc[1][j]);
    }
    #pragma unroll
    for (int j = 0; j < 4; j++){
        acc[0][j] = MFMA(wb.a[1], xf.f[j][1], acc[0][j]);
        acc[1][j] = MFMA(wb.a[3], xf.f[j][1], acc[1][j]);
    }
    __builtin_amdgcn_s_setprio(0);
}

template<bool FIRST>
__device__ __forceinline__ void vgemmW(const WB& wb, const XF& xf, f32x4 (&acc)[4][2]){
    __builtin_amdgcn_s_setprio(1);
    #pragma unroll
    for (int i = 0; i < 4; i++){
        acc[i][0] = FIRST ? MFMA(xf.f[i][0], wb.a[0], Z4) : MFMA(xf.f[i][0], wb.a[0], acc[i][0]);
        acc[i][1] = FIRST ? MFMA(xf.f[i][0], wb.a[2], Z4) : MFMA(xf.f[i][0], wb.a[2], acc[i][1]);
    }
    #pragma unroll
    for (int i = 0; i < 4; i++){
        acc[i][0] = MFMA(xf.f[i][1], wb.a[1], acc[i][0]);
        acc[i][1] = MFMA(xf.f[i][1], wb.a[3], acc[i][1]);
    }
    __builtin_amdgcn_s_setprio(0);
}

template<bool QS>
__device__ __forceinline__ void epiW(f32x4 (&acc)[2][4], float4 bv0, float4 bv1,
                                     u16* dst, int w, int c, int g){
    const int key = c & 7;
    #pragma unroll
    for (int i = 0; i < 2; i++){
        float4 bv = i ? bv1 : bv0;
        const int col0 = (w*2+i)*16 + g*4;
        const int coff = swch(col0>>3, key)*8 + (col0&7);
        #pragma unroll
        for (int j = 0; j < 4; j++){
            int row = j*16 + c;
            float v0 = fmaxf(acc[i][j][0]+bv.x, 0.f);
            float v1 = fmaxf(acc[i][j][1]+bv.y, 0.f);
            float v2 = fmaxf(acc[i][j][2]+bv.z, 0.f);
            float v3 = fmaxf(acc[i][j][3]+bv.w, 0.f);
            if (QS){ v0 *= SCL2; v1 *= SCL2; v2 *= SCL2; v3 *= SCL2; }
            uint2 o; o.x = pk2(v0,v1); o.y = pk2(v2,v3);
            *(uint2*)(dst + row*128 + coff) = o;
        }
    }
}

// ---------------- one MHA layer: R12 schedule, h0 JIT (no hr prefetch) ----------------
template<int LAYER>
__device__ __forceinline__ void mha_layer(const u16* Wu,
                                          u16* IN, u16* OUT,
                                          const float* wsb, const float* h0, size_t rowbase,
                                          int tid, int w, int lane, int c, int g, const u64* mbits,
                                          WB b_q0, WB b_k0, WB b_v0,
                                          WB& nx0, WB& nx1, WB& nx2)
{
    constexpr int UB = 1 + LAYER*8;
    constexpr int BB = 128 + LAYER*512;
    const int key = c & 7;
    const int col00 = w*32 + g*4;
    const int col01 = col00 + 16;
    const int h = w;

    XF xf;
    f32x4 accQ[2][4], accK[2][4];
    f32x4 vacc[4][2];

    loadX(xf, IN, 0, c, g);
    wgemmW<true>(b_q0, xf, accQ);
    WB b_q1 = load_unit<UB+3>(Wu, w, lane);
    wgemmW<true>(b_k0, xf, accK);
    WB b_k1 = load_unit<UB+4>(Wu, w, lane);
    vgemmW<true>(b_v0, xf, vacc);
    WB b_v1 = load_unit<UB+5>(Wu, w, lane);

    loadX(xf, IN, 1, c, g);
    float4 bq0 = *(const float4*)(wsb + BB + col00);
    float4 bq1 = *(const float4*)(wsb + BB + col01);
    wgemmW<false>(b_q1, xf, accQ);
    WB b_o0 = load_unit<UB+6>(Wu, w, lane);
    epiW<true>(accQ, bq0, bq1, OUT, w, c, g);     // Q (exp2-scaled) -> OUT (dead)

    float4 bk0 = *(const float4*)(wsb + BB + 128 + col00);
    float4 bk1 = *(const float4*)(wsb + BB + 128 + col01);
    wgemmW<false>(b_k1, xf, accK);
    WB b_o1 = load_unit<UB+7>(Wu, w, lane);

    float bv0 = wsb[BB + 256 + w*32 + c];
    float bv1 = wsb[BB + 256 + w*32 + 16 + c];
    vgemmW<false>(b_v1, xf, vacc);

    BARX();   // barrier1: all waves' IN reads done -> K may overwrite IN

    epiW<false>(accK, bk0, bk1, IN, w, c, g);     // K -> IN (wave-private cols)

    // scores: mfma(K, Qs) — wave-private columns (h = w)
    f32x4 sc[4][4];
    {
        bf16x8 kf[4];
        #pragma unroll
        for (int kt = 0; kt < 4; kt++)
            kf[kt] = *(const bf16x8*)(IN + (kt*16 + c)*128 + swch(h*4+g, key)*8);
        __builtin_amdgcn_s_setprio(1);
        #pragma unroll
        for (int qt = 0; qt < 4; qt++){
            bf16x8 qf = *(const bf16x8*)(OUT + (qt*16 + c)*128 + swch(h*4+g, key)*8);
            #pragma unroll
            for (int kt = 0; kt < 4; kt++)
                sc[qt][kt] = MFMA(kf[kt], qf, Z4);
        }
        __builtin_amdgcn_s_setprio(0);
    }

    u32 pp[4][4][2];
    float inv[4];
    #pragma unroll
    for (int qt = 0; qt < 4; qt++){
        u64 mb = mbits[qt];
        float sum = 0.f;
        #pragma unroll
        for (int kt = 0; kt < 4; kt++)
            #pragma unroll
            for (int r = 0; r < 4; r++){
                float s = ((mb >> (kt*16 + g*4 + r)) & 1ull) ? sc[qt][kt][r] : -1e30f;
                float e = __builtin_amdgcn_exp2f(s);
                sc[qt][kt][r] = e; sum += e;
            }
        sum += __shfl_xor(sum, 16);
        sum += __shfl_xor(sum, 32);
        inv[qt] = __builtin_amdgcn_rcpf(sum);
        #pragma unroll
        for (int kt = 0; kt < 4; kt++){
            pp[qt][kt][0] = pk2(sc[qt][kt][0], sc[qt][kt][1]);
            pp[qt][kt][1] = pk2(sc[qt][kt][2], sc[qt][kt][3]);
        }
    }

    BARX();   // barrier2: all waves' Q/K reads done -> Q dead (OUT), K dead (IN)

    // V^T -> OUT (own rows)
    #pragma unroll
    for (int j = 0; j < 2; j++){
        int vrow = w*32 + j*16 + c;
        float bv = j ? bv1 : bv0;
        #pragma unroll
        for (int i = 0; i < 4; i++){
            int kk = i >> 1, p = i & 1;
            float v0 = fmaxf(vacc[i][j][0]+bv, 0.f);
            float v1 = fmaxf(vacc[i][j][1]+bv, 0.f);
            float v2 = fmaxf(vacc[i][j][2]+bv, 0.f);
            float v3 = fmaxf(vacc[i][j][3]+bv, 0.f);
            uint2 o; o.x = pk2(v0,v1); o.y = pk2(v2,v3);
            *(uint2*)(OUT + vrow*64 + swch(kk*4+g, key)*8 + p*4) = o;
        }
    }

    // PV (own V^T slab) -> X1 into IN (own cols)
    #pragma unroll
    for (int dt = 0; dt < 2; dt++){
        f32x4 pa[4];
        #pragma unroll
        for (int kk = 0; kk < 2; kk++){
            bf16x8 vt = *(const bf16x8*)(OUT + (h*32 + dt*16 + c)*64 + ((kk*4+g)^key)*8);
            __builtin_amdgcn_s_setprio(1);
            #pragma unroll
            for (int qt = 0; qt < 4; qt++){
                union { u32 u4[4]; bf16x8 v8; } bbv;
                bbv.u4[0]=pp[qt][kk*2][0];   bbv.u4[1]=pp[qt][kk*2][1];
                bbv.u4[2]=pp[qt][kk*2+1][0]; bbv.u4[3]=pp[qt][kk*2+1][1];
                pa[qt] = (kk == 0) ? MFMA(vt, bbv.v8, Z4) : MFMA(vt, bbv.v8, pa[qt]);
            }
            __builtin_amdgcn_s_setprio(0);
        }
        #pragma unroll
        for (int qt = 0; qt < 4; qt++){
            int col = h*32 + dt*16 + g*4;
            float iv = inv[qt];
            uint2 o; o.x = pk2(pa[qt][0]*iv, pa[qt][1]*iv); o.y = pk2(pa[qt][2]*iv, pa[qt][3]*iv);
            *(uint2*)(IN + (qt*16 + c)*128 + swch(col>>3, key)*8 + (col&7)) = o;
        }
    }

    BARX();   // barrier3: all X1 writes visible

    // O-projection from IN(X1) -> OUT
    f32x4 acc[2][4];
    loadX(xf, IN, 0, c, g);
    wgemmW<true>(b_o0, xf, acc);
    loadX(xf, IN, 1, c, g);

    if (LAYER == 1){
        BARX();   // barrier3.5: all waves' X1 reads done -> IN free for h0
        // h0 -> IN bf16 (JIT loads; TLP hides latency at 3 blocks/CU)
        int hrow = tid >> 2, seg = tid & 3;
        const float* hp = h0 + (rowbase + hrow)*128 + seg*32;
        #pragma unroll
        for (int cc = 0; cc < 4; cc++){
            f4v fa = __builtin_nontemporal_load((const f4v*)(hp + cc*8));
            f4v fb = __builtin_nontemporal_load((const f4v*)(hp + cc*8 + 4));
            int p = seg*4 + cc;
            int ps = (p & 8) | ((p ^ (hrow & 7)) & 7);
            uint4 o; o.x = pk2(fa.x,fa.y); o.y = pk2(fa.z,fa.w);
            o.z = pk2(fb.x,fb.y); o.w = pk2(fb.z,fb.w);
            *(uint4*)(IN + hrow*128 + ps*8) = o;
        }
    }

    float4 bo0 = *(const float4*)(wsb + BB + 384 + col00);
    float4 bo1 = *(const float4*)(wsb + BB + 384 + col01);
    wgemmW<false>(b_o1, xf, acc);
    nx0 = load_unit<UB+8>(Wu, w, lane);
    nx1 = load_unit<UB+9>(Wu, w, lane);
    nx2 = load_unit<UB+10>(Wu, w, lane);
    epiW<false>(acc, bo0, bo1, OUT, w, c, g);

    BARX();   // barrier4: OUT (layer result) + h0 (L1) visible
}

// ---------------- main fused kernel: 1 batch item / block, 256 threads, min 3 waves/EU ----------------
__global__ __launch_bounds__(256, 3) void drgn_pipe(
    const float* __restrict__ x, const int* __restrict__ maskg,
    const float* __restrict__ h0, const u16* __restrict__ W16,
    float* __restrict__ out_qs, float* __restrict__ out_h3)
{
    __shared__ __align__(16) u16 SMEM[16384];   // 32768 B: 2 x [64][128] bf16
    u16* A = SMEM;
    u16* B = SMEM + 8192;

    const int tid = threadIdx.x;
    const int w = tid >> 6, lane = tid & 63;
    const int c = lane & 15, g = lane >> 4;
    const int key = c & 7;
    const size_t rowbase = (size_t)blockIdx.x * 64;
    const u16* Wu = W16;
    const float* wsb = (const float*)(W16 + WS_BIAS_OFF);
    const int col00 = w*32 + g*4;
    const int col01 = col00 + 16;

    // ---- prologue: mask bits -> regs (via B transient), x -> A bf16 ----
    u64* MrowT = (u64*)B;
    #pragma unroll 4
    for (int rr = 0; rr < 16; rr++){
        int row = w*16 + rr;
        int mv = __builtin_nontemporal_load(maskg + (rowbase + row)*64 + lane);
        u64 bits = __ballot(mv != 0);
        if (lane == 0) MrowT[row] = bits;
    }
    for (int i = tid; i < 512; i += 256){
        int row = i >> 3, p = i & 7;
        int lc = (p ^ (row & 7)) & 7;
        const float* sp = x + (rowbase + row)*64 + lc*8;
        f4v f0 = __builtin_nontemporal_load((const f4v*)sp);
        f4v f1 = __builtin_nontemporal_load((const f4v*)(sp + 4));
        uint4 o; o.x = pk2(f0.x,f0.y); o.y = pk2(f0.z,f0.w);
        o.z = pk2(f1.x,f1.y); o.w = pk2(f1.z,f1.w);
        *(uint4*)(A + row*128 + p*8) = o;
    }
    WB b_enc = load_unit<0>(Wu, w, lane);
    WB n0 = load_unit<1>(Wu, w, lane);
    WB n1 = load_unit<2>(Wu, w, lane);
    WB n2 = load_unit<3>(Wu, w, lane);
    __syncthreads();
    u64 mbits[4];
    #pragma unroll
    for (int qt = 0; qt < 4; qt++) mbits[qt] = MrowT[qt*16 + c];

    // ---- encoder (unit 0): B = relu(x @ enc^T + b) ----
    {
        XF xf;
        f32x4 acc[2][4];
        float4 b0 = *(const float4*)(wsb + col00);
        float4 b1 = *(const float4*)(wsb + col01);
        loadX(xf, A, 0, c, g);
        wgemmW<true>(b_enc, xf, acc);
        BARX();   // all mbits reads + A(x) reads done -> B overwrite safe
        epiW<false>(acc, b0, b1, B, w, c, g);
    }
    BARX();       // enc-out visible; A dead

    // ---- two MHA layers (ping-pong) ----
    mha_layer<0>(Wu, B, A, wsb, h0, rowbase, tid, w, lane, c, g, mbits,
                 n0, n1, n2, n0, n1, n2);
    mha_layer<1>(Wu, A, B, wsb, h0, rowbase, tid, w, lane, c, g, mbits,
                 n0, n1, n2, n0, n1, n2);
    // exit: B = h2, A = h0(bf16); n0=u17(r_ih0), n1=u18(z_ih0), n2=u19(r_ih1)

    // ---- GRU sequential gates (peak = aI+aH = 64 acc regs) ----
    u32 rrP[2][4][2], zzP[2][4][2];
    XF xf;
    WB u20, u22, u24, u25, u26, u27, g29, g30;
    {   // r gate: units 17,19 (ih), 21,23 (hh)
        f32x4 aI[2][4], aH[2][4];
        loadX(xf, B, 0, c, g);
        wgemmW<true>(n0, xf, aI);
        WB u21 = load_unit<21>(Wu, w, lane);
        loadX(xf, B, 1, c, g);
        wgemmW<false>(n2, xf, aI);
        WB u23 = load_unit<23>(Wu, w, lane);
        loadX(xf, A, 0, c, g);
        wgemmW<true>(u21, xf, aH);
        u20 = load_unit<20>(Wu, w, lane);
        loadX(xf, A, 1, c, g);
        wgemmW<false>(u23, xf, aH);
        u22 = load_unit<22>(Wu, w, lane);

        float4 bi0 = *(const float4*)(wsb + 1152 + col00);
        float4 bi1 = *(const float4*)(wsb + 1152 + col01);
        float4 bh0 = *(const float4*)(wsb + 1536 + col00);
        float4 bh1 = *(const float4*)(wsb + 1536 + col01);
        #pragma unroll
        for (int i = 0; i < 2; i++){
            float4 bi = i ? bi1 : bi0; float4 bh = i ? bh1 : bh0;
            #pragma unroll
            for (int j = 0; j < 4; j++){
                float s0 = sigx(aI[i][j][0] + bi.x + aH[i][j][0] + bh.x);
                float s1 = sigx(aI[i][j][1] + bi.y + aH[i][j][1] + bh.y);
                float s2 = sigx(aI[i][j][2] + bi.z + aH[i][j][2] + bh.z);
                float s3 = sigx(aI[i][j][3] + bi.w + aH[i][j][3] + bh.w);
                rrP[i][j][0] = pk2(s0, s1); rrP[i][j][1] = pk2(s2, s3);
            }
        }
    }
    {   // z gate: units 18,20 (ih), 22,24 (hh)
        f32x4 aI[2][4], aH[2][4];
        loadX(xf, B, 0, c, g);
        wgemmW<true>(n1, xf, aI);
        u24 = load_unit<24>(Wu, w, lane);
        loadX(xf, B, 1, c, g);
        wgemmW<false>(u20, xf, aI);
        u25 = load_unit<25>(Wu, w, lane);
        loadX(xf, A, 0, c, g);
        wgemmW<true>(u22, xf, aH);
        u26 = load_unit<26>(Wu, w, lane);
        loadX(xf, A, 1, c, g);
        wgemmW<false>(u24, xf, aH);
        u27 = load_unit<27>(Wu, w, lane);

        float4 bi0 = *(const float4*)(wsb + 1152 + 128 + col00);
        float4 bi1 = *(const float4*)(wsb + 1152 + 128 + col01);
        float4 bh0 = *(const float4*)(wsb + 1536 + 128 + col00);
        float4 bh1 = *(const float4*)(wsb + 1536 + 128 + col01);
        #pragma unroll
        for (int i = 0; i < 2; i++){
            float4 bi = i ? bi1 : bi0; float4 bh = i ? bh1 : bh0;
            #pragma unroll
            for (int j = 0; j < 4; j++){
                float s0 = sigx(aI[i][j][0] + bi.x + aH[i][j][0] + bh.x);
                float s1 = sigx(aI[i][j][1] + bi.y + aH[i][j][1] + bh.y);
                float s2 = sigx(aI[i][j][2] + bi.z + aH[i][j][2] + bh.z);
                float s3 = sigx(aI[i][j][3] + bi.w + aH[i][j][3] + bh.w);
                zzP[i][j][0] = pk2(s0, s1); zzP[i][j][1] = pk2(s2, s3);
            }
        }
    }
    {   // n gate: units 25,26 (ih), 27,28 (hh); combine + h3 stores
        f32x4 aIn[2][4], aHn[2][4];
        loadX(xf, B, 0, c, g);
        wgemmW<true>(u25, xf, aIn);
        WB u28 = load_unit<28>(Wu, w, lane);
        loadX(xf, B, 1, c, g);
        wgemmW<false>(u26, xf, aIn);
        g29 = load_unit<29>(Wu, w, lane);
        loadX(xf, A, 0, c, g);
        wgemmW<true>(u27, xf, aHn);
        g30 = load_unit<30>(Wu, w, lane);
        loadX(xf, A, 1, c, g);
        wgemmW<false>(u28, xf, aHn);

        float4 bin0 = *(const float4*)(wsb + 1152 + 256 + col00);
        float4 bin1 = *(const float4*)(wsb + 1152 + 256 + col01);
        float4 bhn0 = *(const float4*)(wsb + 1536 + 256 + col00);
        float4 bhn1 = *(const float4*)(wsb + 1536 + 256 + col01);

        BARX();   // all waves' B/A reads done -> h3 may overwrite B

        #pragma unroll
        for (int i = 0; i < 2; i++){
            float4 bi = i ? bin1 : bin0; float4 bh = i ? bhn1 : bhn0;
            int col0 = w*32 + i*16 + g*4;
            int coff = swch(col0>>3, key)*8 + (col0&7);
            #pragma unroll
            for (int j = 0; j < 4; j++){
                int row = j*16 + c;
                uint2 hv = *(const uint2*)(A + row*128 + coff);
                float h0v[4] = { b2f((u16)(hv.x & 0xffffu)), b2f((u16)(hv.x >> 16)),
                                 b2f((u16)(hv.y & 0xffffu)), b2f((u16)(hv.y >> 16)) };
                f4v h3o;
                #pragma unroll
                for (int r = 0; r < 4; r++){
                    float rr_ = b2f((u16)(rrP[i][j][r>>1] >> ((r&1)*16)));
                    float zv  = b2f((u16)(zzP[i][j][r>>1] >> ((r&1)*16)));
                    float xn = aIn[i][j][r] + (&bi.x)[r] + rr_*(aHn[i][j][r] + (&bh.x)[r]);
                    float e2 = __builtin_amdgcn_exp2f(-2.f*L2E*fabsf(xn));
                    float th = (1.f - e2)*__builtin_amdgcn_rcpf(1.f + e2);
                    th = (xn >= 0.f) ? th : -th;
                    h3o[r] = (1.f - zv)*th + zv*h0v[r];
                }
                uint2 o; o.x = pk2(h3o[0],h3o[1]); o.y = pk2(h3o[2],h3o[3]);
                *(uint2*)(B + row*128 + coff) = o;   // h3 bf16 -> B (for qs GEMM)
                __builtin_nontemporal_store(h3o, (f4v*)(out_h3 + (rowbase + row)*128 + col0));
            }
        }
    }
    BARX();   // h3 visible

    // ---- final linear (units 29,30) + qs stores ----
    {
        f32x4 qa[2][4];
        float4 lb0 = (col00 < 20) ? *(const float4*)(wsb + 1920 + col00) : (float4){0.f,0.f,0.f,0.f};
        float4 lb1 = (col01 < 20) ? *(const float4*)(wsb + 1920 + col01) : (float4){0.f,0.f,0.f,0.f};
        loadX(xf, B, 0, c, g);
        wgemmW<true>(g29, xf, qa);
        loadX(xf, B, 1, c, g);
        wgemmW<false>(g30, xf, qa);

        #pragma unroll
        for (int i = 0; i < 2; i++){
            int col0 = w*32 + i*16 + g*4;
            if (col0 < 20){
                float4 lb = i ? lb1 : lb0;
                #pragma unroll
                for (int j = 0; j < 4; j++){
                    int row = j*16 + c;
                    f4v o;
                    o.x = qa[i][j][0]+lb.x; o.y = qa[i][j][1]+lb.y;
                    o.z = qa[i][j][2]+lb.z; o.w = qa[i][j][3]+lb.w;
                    __builtin_nontemporal_store(o, (f4v*)(out_qs + (rowbase + row)*20 + col0));
                }
            }
        }
    }
}

extern "C" void kernel_launch(void* const* d_in, const int* in_sizes, int n_in,
                              void* d_out, int out_size, void* d_ws, size_t ws_size,
                              hipStream_t stream) {
    const float* x     = (const float*)d_in[0];
    const int*   mask  = (const int*)  d_in[1];
    const float* h0    = (const float*)d_in[2];
    const float* enc_w = (const float*)d_in[3];
    const float* enc_b = (const float*)d_in[4];
    const float* q1_w  = (const float*)d_in[5];  const float* q1_b = (const float*)d_in[6];
    const float* k1_w  = (const float*)d_in[7];  const float* k1_b = (const float*)d_in[8];
    const float* v1_w  = (const float*)d_in[9];  const float* v1_b = (const float*)d_in[10];
    const float* o1_w  = (const float*)d_in[11]; const float* o1_b = (const float*)d_in[12];
    const float* q2_w  = (const float*)d_in[13]; const float* q2_b = (const float*)d_in[14];
    const float* k2_w  = (const float*)d_in[15]; const float* k2_b = (const float*)d_in[16];
    const float* v2_w  = (const float*)d_in[17]; const float* v2_b = (const float*)d_in[18];
    const float* o2_w  = (const float*)d_in[19]; const float* o2_b = (const float*)d_in[20];
    const float* gwih  = (const float*)d_in[21]; const float* gwhh = (const float*)d_in[22];
    const float* gbih  = (const float*)d_in[23]; const float* gbhh = (const float*)d_in[24];
    const float* lin_w = (const float*)d_in[25]; const float* lin_b = (const float*)d_in[26];

    const int bs = in_sizes[0] / (64 * 64);           // 4096
    float* out_qs = (float*)d_out;
    float* out_h3 = out_qs + (size_t)bs * 64 * 20;
    u16* W16 = (u16*)d_ws;

    const int total = NUNITS*8192 + NBIAS;
    hipLaunchKernelGGL(convert_weights, dim3((total + 255) / 256), dim3(256), 0, stream,
                       enc_w, q1_w, k1_w, v1_w, o1_w, q2_w, k2_w, v2_w, o2_w,
                       gwih, gwhh, lin_w,
                       enc_b, q1_b, k1_b, v1_b, o1_b, q2_b, k2_b, v2_b, o2_b,
                       gbih, gbhh, lin_b, W16);
    hipLaunchKernelGGL(drgn_pipe, dim3(bs), dim3(256), 0, stream,
                       x, mask, h0, W16, out_qs, out_h3);
}

// Round 15
// 303.516 us; speedup vs baseline: 2.2594x; 1.9286x over previous
//
#include <hip/hip_runtime.h>
#include <hip/hip_bf16.h>

typedef unsigned int u32;
typedef unsigned short u16;
typedef unsigned long long u64;

using bf16x8 = __attribute__((ext_vector_type(8))) short;
using f32x4  = __attribute__((ext_vector_type(4))) float;
typedef float f4v __attribute__((ext_vector_type(4)));

#define NUNITS 31
#define WS_BIAS_OFF (NUNITS*8192)
#define NBIAS 1952
#define SCL2 0.25503512f     // 1/sqrt(32) * log2(e)
#define L2E  1.4426950408889634f

__device__ __forceinline__ u32 pk2(float a, float b){
    __hip_bfloat162 h = __float22bfloat162_rn(make_float2(a, b));
    union { __hip_bfloat162 h2; u32 u; } cv; cv.h2 = h; return cv.u;
}
__device__ __forceinline__ float b2f(u16 v){ return __uint_as_float(((u32)v) << 16); }
__device__ __forceinline__ int swch(int chunk, int key){ return (chunk & ~7) | ((chunk ^ key) & 7); }
__device__ __forceinline__ float sigx(float v){
    return __builtin_amdgcn_rcpf(1.f + __builtin_amdgcn_exp2f(-L2E * v));
}

// ---------------- weight pre-conversion (identical layout to R7-R12) ----------------
__global__ __launch_bounds__(256) void convert_weights(
    const float* __restrict__ enc_w,
    const float* __restrict__ q1, const float* __restrict__ k1,
    const float* __restrict__ v1, const float* __restrict__ o1,
    const float* __restrict__ q2, const float* __restrict__ k2,
    const float* __restrict__ v2, const float* __restrict__ o2,
    const float* __restrict__ gih, const float* __restrict__ ghh,
    const float* __restrict__ lin,
    const float* __restrict__ enc_b,
    const float* __restrict__ q1b, const float* __restrict__ k1b,
    const float* __restrict__ v1b, const float* __restrict__ o1b,
    const float* __restrict__ q2b, const float* __restrict__ k2b,
    const float* __restrict__ v2b, const float* __restrict__ o2b,
    const float* __restrict__ gbih, const float* __restrict__ gbhh,
    const float* __restrict__ linb,
    u16* __restrict__ dst)
{
    int idx = blockIdx.x*256 + threadIdx.x;
    if (idx < NUNITS*8192){
        int u = idx >> 13, rem = idx & 8191;
        int w = rem >> 11;
        int t = (rem >> 9) & 3;
        int l = (rem >> 3) & 63;
        int e = idx & 7;
        int i = t >> 1, kk = t & 1;
        int oc = (w*2 + i)*16 + (l & 15);
        int kl = kk*32 + (l >> 4)*8 + e;
        float val;
        if (u == 0){
            val = enc_w[oc*64 + kl];
        } else if (u <= 16){
            int v = u - 1; int L = v >> 3; int r8 = v & 7;
            int mat, kh;
            if (r8 < 6){ mat = r8 % 3; kh = r8 / 3; } else { mat = 3; kh = r8 - 6; }
            const float* s;
            if (L == 0){ s = (mat==0)?q1:(mat==1)?k1:(mat==2)?v1:o1; }
            else       { s = (mat==0)?q2:(mat==1)?k2:(mat==2)?v2:o2; }
            val = s[oc*128 + kh*64 + kl];
        } else if (u <= 28){
            int v = u - 17;
            int gate, kh; const float* s;
            if (v < 8){ gate = v & 1; kh = (v >> 1) & 1; s = (v >= 4) ? ghh : gih; }
            else      { int w8 = v - 8; gate = 2; kh = w8 & 1; s = (w8 >= 2) ? ghh : gih; }
            val = s[(gate*128 + oc)*128 + kh*64 + kl];
        } else {
            int kh = u - 29;
            val = (oc < 20) ? lin[oc*128 + kh*64 + kl] : 0.f;
        }
        __hip_bfloat16 hv = __float2bfloat16(val);
        union { __hip_bfloat16 h; u16 us; } cv; cv.h = hv;
        dst[idx] = cv.us;
    } else if (idx < NUNITS*8192 + NBIAS){
        int i = idx - NUNITS*8192;
        float val;
        if      (i < 128)  val = enc_b[i];
        else if (i < 256)  val = q1b[i-128];
        else if (i < 384)  val = k1b[i-256];
        else if (i < 512)  val = v1b[i-384];
        else if (i < 640)  val = o1b[i-512];
        else if (i < 768)  val = q2b[i-640];
        else if (i < 896)  val = k2b[i-768];
        else if (i < 1024) val = v2b[i-896];
        else if (i < 1152) val = o2b[i-1024];
        else if (i < 1536) val = gbih[i-1152];
        else if (i < 1920) val = gbhh[i-1536];
        else if (i < 1940) val = linb[i-1920];
        else               val = 0.f;
        ((float*)(dst + NUNITS*8192))[i] = val;
    }
}

// ---------------- primitives ----------------
#define BARX() do{ asm volatile("s_waitcnt lgkmcnt(0)" ::: "memory"); \
                   __builtin_amdgcn_s_barrier(); \
                   asm volatile("" ::: "memory"); }while(0)

struct WB { bf16x8 a[4]; };   // a[i*2+kk]

template<int U>
__device__ __forceinline__ WB load_unit(const u16* Wu, int w, int lane){
    const u16* p = Wu + U*8192 + w*2048 + lane*8;
    WB b;
    b.a[0] = *(const bf16x8*)(p);
    b.a[1] = *(const bf16x8*)(p + 512);
    b.a[2] = *(const bf16x8*)(p + 1024);
    b.a[3] = *(const bf16x8*)(p + 1536);
    return b;
}

#define Z4 ((f32x4){0.f,0.f,0.f,0.f})
#define MFMA(a,b,c) __builtin_amdgcn_mfma_f32_16x16x32_bf16((a),(b),(c),0,0,0)

struct XF { bf16x8 f[4][2]; };

__device__ __forceinline__ void loadX(XF& xf, const u16* X, int kh, int c, int g){
    const int key = c & 7;
    #pragma unroll
    for (int kk = 0; kk < 2; kk++){
        const int pw = (kk*4 + g) ^ key;
        #pragma unroll
        for (int j = 0; j < 4; j++)
            xf.f[j][kk] = *(const bf16x8*)(X + (j*16 + c)*128 + (kh*8 + pw)*8);
    }
}

template<bool FIRST>
__device__ __forceinline__ void wgemmW(const WB& wb, const XF& xf, f32x4 (&acc)[2][4]){
    __builtin_amdgcn_s_setprio(1);
    #pragma unroll
    for (int j = 0; j < 4; j++){
        acc[0][j] = FIRST ? MFMA(wb.a[0], xf.f[j][0], Z4) : MFMA(wb.a[0], xf.f[j][0], acc[0][j]);
        acc[1][j] = FIRST ? MFMA(wb.a[2], xf.f[j][0], Z4) : MFMA(wb.a[2], xf.f[j][0], acc[1][j]);
    }
    #pragma unroll
    for (int j = 0; j < 4; j++){
        acc[0][j] = MFMA(wb.a[1], xf.f[j][1], acc[0][j]);
        acc[1][j] = MFMA(wb.a[3], xf.f[j][1], acc[1][j]);
    }
    __builtin_amdgcn_s_setprio(0);
}

template<bool FIRST>
__device__ __forceinline__ void vgemmW(const WB& wb, const XF& xf, f32x4 (&acc)[4][2]){
    __builtin_amdgcn_s_setprio(1);
    #pragma unroll
    for (int i = 0; i < 4; i++){
        acc[i][0] = FIRST ? MFMA(xf.f[i][0], wb.a[0], Z4) : MFMA(xf.f[i][0], wb.a[0], acc[i][0]);
        acc[i][1] = FIRST ? MFMA(xf.f[i][0], wb.a[2], Z4) : MFMA(xf.f[i][0], wb.a[2], acc[i][1]);
    }
    #pragma unroll
    for (int i = 0; i < 4; i++){
        acc[i][0] = MFMA(xf.f[i][1], wb.a[1], acc[i][0]);
        acc[i][1] = MFMA(xf.f[i][1], wb.a[3], acc[i][1]);
    }
    __builtin_amdgcn_s_setprio(0);
}

template<bool QS>
__device__ __forceinline__ void epiW(f32x4 (&acc)[2][4], float4 bv0, float4 bv1,
                                     u16* dst, int w, int c, int g){
    const int key = c & 7;
    #pragma unroll
    for (int i = 0; i < 2; i++){
        float4 bv = i ? bv1 : bv0;
        const int col0 = (w*2+i)*16 + g*4;
        const int coff = swch(col0>>3, key)*8 + (col0&7);
        #pragma unroll
        for (int j = 0; j < 4; j++){
            int row = j*16 + c;
            float v0 = fmaxf(acc[i][j][0]+bv.x, 0.f);
            float v1 = fmaxf(acc[i][j][1]+bv.y, 0.f);
            float v2 = fmaxf(acc[i][j][2]+bv.z, 0.f);
            float v3 = fmaxf(acc[i][j][3]+bv.w, 0.f);
            if (QS){ v0 *= SCL2; v1 *= SCL2; v2 *= SCL2; v3 *= SCL2; }
            uint2 o; o.x = pk2(v0,v1); o.y = pk2(v2,v3);
            *(uint2*)(dst + row*128 + coff) = o;
        }
    }
}

// ---------------- one MHA layer: R8 schedule on 2-buffer ping-pong ----------------
// entry: IN = layer input (visible); OUT = dead.
// exit : OUT = layer output (visible); IN = dead (L1: h0-bf16).
template<int LAYER>
__device__ __forceinline__ void mha_layer(const u16* Wu,
                                          u16* IN, u16* OUT,
                                          const float* wsb, const float* h0, size_t rowbase,
                                          int tid, int w, int lane, int c, int g, const u64* mbits,
                                          WB b_q0, WB b_k0, WB b_v0,
                                          WB& nx0, WB& nx1, WB& nx2)
{
    constexpr int UB = 1 + LAYER*8;
    constexpr int BB = 128 + LAYER*512;
    const int key = c & 7;
    const int col00 = w*32 + g*4;
    const int col01 = col00 + 16;
    const int h = w;

    XF xf;
    f32x4 accQ[2][4], accK[2][4];
    f32x4 vacc[4][2];

    loadX(xf, IN, 0, c, g);
    wgemmW<true>(b_q0, xf, accQ);
    WB b_q1 = load_unit<UB+3>(Wu, w, lane);
    wgemmW<true>(b_k0, xf, accK);
    WB b_k1 = load_unit<UB+4>(Wu, w, lane);
    vgemmW<true>(b_v0, xf, vacc);
    WB b_v1 = load_unit<UB+5>(Wu, w, lane);

    loadX(xf, IN, 1, c, g);
    float4 bq0 = *(const float4*)(wsb + BB + col00);
    float4 bq1 = *(const float4*)(wsb + BB + col01);
    wgemmW<false>(b_q1, xf, accQ);
    WB b_o0 = load_unit<UB+6>(Wu, w, lane);
    epiW<true>(accQ, bq0, bq1, OUT, w, c, g);     // Q (exp2-scaled) -> OUT (dead)

    float4 bk0 = *(const float4*)(wsb + BB + 128 + col00);
    float4 bk1 = *(const float4*)(wsb + BB + 128 + col01);
    wgemmW<false>(b_k1, xf, accK);
    WB b_o1 = load_unit<UB+7>(Wu, w, lane);

    float bv0 = wsb[BB + 256 + w*32 + c];
    float bv1 = wsb[BB + 256 + w*32 + 16 + c];
    vgemmW<false>(b_v1, xf, vacc);

    BARX();   // barrier1: all waves' IN reads done -> K may overwrite IN

    epiW<false>(accK, bk0, bk1, IN, w, c, g);     // K -> IN (wave-private cols)

    // scores: mfma(K, Qs) — wave-private columns (h = w)
    f32x4 sc[4][4];
    {
        bf16x8 kf[4];
        #pragma unroll
        for (int kt = 0; kt < 4; kt++)
            kf[kt] = *(const bf16x8*)(IN + (kt*16 + c)*128 + swch(h*4+g, key)*8);
        __builtin_amdgcn_s_setprio(1);
        #pragma unroll
        for (int qt = 0; qt < 4; qt++){
            bf16x8 qf = *(const bf16x8*)(OUT + (qt*16 + c)*128 + swch(h*4+g, key)*8);
            #pragma unroll
            for (int kt = 0; kt < 4; kt++)
                sc[qt][kt] = MFMA(kf[kt], qf, Z4);
        }
        __builtin_amdgcn_s_setprio(0);
    }

    // T14 issue-early: h0 loads during softmax (LAYER 1)
    f4v hr[8];
    if (LAYER == 1){
        const float* hp = h0 + (rowbase + (tid>>2))*128 + (tid&3)*32;
        #pragma unroll
        for (int t = 0; t < 8; t++)
            hr[t] = __builtin_nontemporal_load((const f4v*)(hp + t*4));
    }

    u32 pp[4][4][2];
    float inv[4];
    #pragma unroll
    for (int qt = 0; qt < 4; qt++){
        u64 mb = mbits[qt];
        float sum = 0.f;
        #pragma unroll
        for (int kt = 0; kt < 4; kt++)
            #pragma unroll
            for (int r = 0; r < 4; r++){
                float s = ((mb >> (kt*16 + g*4 + r)) & 1ull) ? sc[qt][kt][r] : -1e30f;
                float e = __builtin_amdgcn_exp2f(s);
                sc[qt][kt][r] = e; sum += e;
            }
        sum += __shfl_xor(sum, 16);
        sum += __shfl_xor(sum, 32);
        inv[qt] = __builtin_amdgcn_rcpf(sum);
        #pragma unroll
        for (int kt = 0; kt < 4; kt++){
            pp[qt][kt][0] = pk2(sc[qt][kt][0], sc[qt][kt][1]);
            pp[qt][kt][1] = pk2(sc[qt][kt][2], sc[qt][kt][3]);
        }
    }

    BARX();   // barrier2: all waves' Q/K reads done -> Q dead (OUT), K dead (IN)

    // V^T -> OUT (own rows)
    #pragma unroll
    for (int j = 0; j < 2; j++){
        int vrow = w*32 + j*16 + c;
        float bv = j ? bv1 : bv0;
        #pragma unroll
        for (int i = 0; i < 4; i++){
            int kk = i >> 1, p = i & 1;
            float v0 = fmaxf(vacc[i][j][0]+bv, 0.f);
            float v1 = fmaxf(vacc[i][j][1]+bv, 0.f);
            float v2 = fmaxf(vacc[i][j][2]+bv, 0.f);
            float v3 = fmaxf(vacc[i][j][3]+bv, 0.f);
            uint2 o; o.x = pk2(v0,v1); o.y = pk2(v2,v3);
            *(uint2*)(OUT + vrow*64 + swch(kk*4+g, key)*8 + p*4) = o;
        }
    }

    // PV (own V^T slab) -> X1 into IN (own cols)
    #pragma unroll
    for (int dt = 0; dt < 2; dt++){
        f32x4 pa[4];
        #pragma unroll
        for (int kk = 0; kk < 2; kk++){
            bf16x8 vt = *(const bf16x8*)(OUT + (h*32 + dt*16 + c)*64 + ((kk*4+g)^key)*8);
            __builtin_amdgcn_s_setprio(1);
            #pragma unroll
            for (int qt = 0; qt < 4; qt++){
                union { u32 u4[4]; bf16x8 v8; } bbv;
                bbv.u4[0]=pp[qt][kk*2][0];   bbv.u4[1]=pp[qt][kk*2][1];
                bbv.u4[2]=pp[qt][kk*2+1][0]; bbv.u4[3]=pp[qt][kk*2+1][1];
                pa[qt] = (kk == 0) ? MFMA(vt, bbv.v8, Z4) : MFMA(vt, bbv.v8, pa[qt]);
            }
            __builtin_amdgcn_s_setprio(0);
        }
        #pragma unroll
        for (int qt = 0; qt < 4; qt++){
            int col = h*32 + dt*16 + g*4;
            float iv = inv[qt];
            uint2 o; o.x = pk2(pa[qt][0]*iv, pa[qt][1]*iv); o.y = pk2(pa[qt][2]*iv, pa[qt][3]*iv);
            *(uint2*)(IN + (qt*16 + c)*128 + swch(col>>3, key)*8 + (col&7)) = o;
        }
    }

    BARX();   // barrier3: all X1 writes visible

    // O-projection from IN(X1) -> OUT
    f32x4 acc[2][4];
    loadX(xf, IN, 0, c, g);
    wgemmW<true>(b_o0, xf, acc);
    loadX(xf, IN, 1, c, g);

    if (LAYER == 1){
        BARX();   // barrier3.5: all waves' X1 reads done -> IN free for h0
        int hrow = tid >> 2, seg = tid & 3;
        #pragma unroll
        for (int cc = 0; cc < 4; cc++){
            int p = seg*4 + cc;
            int ps = (p & 8) | ((p ^ (hrow & 7)) & 7);
            f4v fa = hr[cc*2], fb = hr[cc*2+1];
            uint4 o; o.x = pk2(fa.x,fa.y); o.y = pk2(fa.z,fa.w);
            o.z = pk2(fb.x,fb.y); o.w = pk2(fb.z,fb.w);
            *(uint4*)(IN + hrow*128 + ps*8) = o;
        }
    }

    float4 bo0 = *(const float4*)(wsb + BB + 384 + col00);
    float4 bo1 = *(const float4*)(wsb + BB + 384 + col01);
    wgemmW<false>(b_o1, xf, acc);
    nx0 = load_unit<UB+8>(Wu, w, lane);
    nx1 = load_unit<UB+9>(Wu, w, lane);
    nx2 = load_unit<UB+10>(Wu, w, lane);
    epiW<false>(acc, bo0, bo1, OUT, w, c, g);

    BARX();   // barrier4: OUT (layer result) + h0 (L1) visible
}

// ---------------- main fused kernel: 1 batch item / block, 256 threads ----------------
__global__ __launch_bounds__(256, 2) void drgn_pipe(
    const float* __restrict__ x, const int* __restrict__ maskg,
    const float* __restrict__ h0, const u16* __restrict__ W16,
    float* __restrict__ out_qs, float* __restrict__ out_h3)
{
    __shared__ __align__(16) u16 SMEM[16384];   // 32768 B: 2 x [64][128] bf16
    u16* A = SMEM;
    u16* B = SMEM + 8192;

    const int tid = threadIdx.x;
    const int w = tid >> 6, lane = tid & 63;
    const int c = lane & 15, g = lane >> 4;
    const int key = c & 7;
    const size_t rowbase = (size_t)blockIdx.x * 64;
    const u16* Wu = W16;
    const float* wsb = (const float*)(W16 + WS_BIAS_OFF);
    const int col00 = w*32 + g*4;
    const int col01 = col00 + 16;

    // ---- prologue: mask bits -> regs (via B transient), x -> A bf16 ----
    u64* MrowT = (u64*)B;
    #pragma unroll 4
    for (int rr = 0; rr < 16; rr++){
        int row = w*16 + rr;
        int mv = __builtin_nontemporal_load(maskg + (rowbase + row)*64 + lane);
        u64 bits = __ballot(mv != 0);
        if (lane == 0) MrowT[row] = bits;
    }
    for (int i = tid; i < 512; i += 256){
        int row = i >> 3, p = i & 7;
        int lc = (p ^ (row & 7)) & 7;
        const float* sp = x + (rowbase + row)*64 + lc*8;
        f4v f0 = __builtin_nontemporal_load((const f4v*)sp);
        f4v f1 = __builtin_nontemporal_load((const f4v*)(sp + 4));
        uint4 o; o.x = pk2(f0.x,f0.y); o.y = pk2(f0.z,f0.w);
        o.z = pk2(f1.x,f1.y); o.w = pk2(f1.z,f1.w);
        *(uint4*)(A + row*128 + p*8) = o;
    }
    WB b_enc = load_unit<0>(Wu, w, lane);
    WB n0 = load_unit<1>(Wu, w, lane);
    WB n1 = load_unit<2>(Wu, w, lane);
    WB n2 = load_unit<3>(Wu, w, lane);
    __syncthreads();
    u64 mbits[4];
    #pragma unroll
    for (int qt = 0; qt < 4; qt++) mbits[qt] = MrowT[qt*16 + c];

    // ---- encoder (unit 0): B = relu(x @ enc^T + b) ----
    {
        XF xf;
        f32x4 acc[2][4];
        float4 b0 = *(const float4*)(wsb + col00);
        float4 b1 = *(const float4*)(wsb + col01);
        loadX(xf, A, 0, c, g);
        wgemmW<true>(b_enc, xf, acc);
        BARX();   // all mbits reads + A(x) reads done -> B overwrite safe
        epiW<false>(acc, b0, b1, B, w, c, g);
    }
    BARX();       // enc-out visible; A dead

    // ---- two MHA layers (ping-pong) ----
    mha_layer<0>(Wu, B, A, wsb, h0, rowbase, tid, w, lane, c, g, mbits,
                 n0, n1, n2, n0, n1, n2);
    mha_layer<1>(Wu, A, B, wsb, h0, rowbase, tid, w, lane, c, g, mbits,
                 n0, n1, n2, n0, n1, n2);   // exit: B = h2, A = h0(bf16); n = g17,18,19

    // ---- GRU: h2 = B, h0 = A ----
    XF xf;
    float rrA[2][4][4], zzA[2][4][4];
    WB g29, g30;
    {
        f32x4 aIr[2][4], aIz[2][4], aHr[2][4], aHz[2][4];
        loadX(xf, B, 0, c, g);
        wgemmW<true>(n0, xf, aIr);                       // r_ih0
        WB g20 = load_unit<20>(Wu, w, lane);
        wgemmW<true>(n1, xf, aIz);                       // z_ih0
        WB g21 = load_unit<21>(Wu, w, lane);
        loadX(xf, B, 1, c, g);
        wgemmW<false>(n2, xf, aIr);                      // r_ih1
        WB g22 = load_unit<22>(Wu, w, lane);
        wgemmW<false>(g20, xf, aIz);                     // z_ih1
        WB g23 = load_unit<23>(Wu, w, lane);
        loadX(xf, A, 0, c, g);
        wgemmW<true>(g21, xf, aHr);                      // r_hh0
        WB g24 = load_unit<24>(Wu, w, lane);
        wgemmW<true>(g22, xf, aHz);                      // z_hh0
        WB g25 = load_unit<25>(Wu, w, lane);
        loadX(xf, A, 1, c, g);
        wgemmW<false>(g23, xf, aHr);                     // r_hh1
        WB g26 = load_unit<26>(Wu, w, lane);
        wgemmW<false>(g24, xf, aHz);                     // z_hh1
        WB g27 = load_unit<27>(Wu, w, lane);

        float4 bir0 = *(const float4*)(wsb + 1152 + col00);
        float4 bir1 = *(const float4*)(wsb + 1152 + col01);
        float4 bhr0 = *(const float4*)(wsb + 1536 + col00);
        float4 bhr1 = *(const float4*)(wsb + 1536 + col01);
        float4 biz0 = *(const float4*)(wsb + 1152 + 128 + col00);
        float4 biz1 = *(const float4*)(wsb + 1152 + 128 + col01);
        float4 bhz0 = *(const float4*)(wsb + 1536 + 128 + col00);
        float4 bhz1 = *(const float4*)(wsb + 1536 + 128 + col01);
        #pragma unroll
        for (int i = 0; i < 2; i++){
            float4 bir = i ? bir1 : bir0; float4 bhr = i ? bhr1 : bhr0;
            float4 biz = i ? biz1 : biz0; float4 bhz = i ? bhz1 : bhz0;
            #pragma unroll
            for (int j = 0; j < 4; j++)
                #pragma unroll
                for (int r = 0; r < 4; r++){
                    rrA[i][j][r] = sigx(aIr[i][j][r] + (&bir.x)[r] + aHr[i][j][r] + (&bhr.x)[r]);
                    zzA[i][j][r] = sigx(aIz[i][j][r] + (&biz.x)[r] + aHz[i][j][r] + (&bhz.x)[r]);
                }
        }

        // n gate
        f32x4 aIn[2][4], aHn[2][4];
        loadX(xf, B, 0, c, g);
        wgemmW<true>(g25, xf, aIn);
        WB g28 = load_unit<28>(Wu, w, lane);
        loadX(xf, B, 1, c, g);
        wgemmW<false>(g26, xf, aIn);
        g29 = load_unit<29>(Wu, w, lane);
        loadX(xf, A, 0, c, g);
        wgemmW<true>(g27, xf, aHn);
        g30 = load_unit<30>(Wu, w, lane);
        loadX(xf, A, 1, c, g);
        wgemmW<false>(g28, xf, aHn);

        float4 bin0 = *(const float4*)(wsb + 1152 + 256 + col00);
        float4 bin1 = *(const float4*)(wsb + 1152 + 256 + col01);
        float4 bhn0 = *(const float4*)(wsb + 1536 + 256 + col00);
        float4 bhn1 = *(const float4*)(wsb + 1536 + 256 + col01);

        BARX();   // all waves' B/A reads done -> h3 may overwrite B

        #pragma unroll
        for (int i = 0; i < 2; i++){
            float4 bi = i ? bin1 : bin0; float4 bh = i ? bhn1 : bhn0;
            int col0 = w*32 + i*16 + g*4;
            int coff = swch(col0>>3, key)*8 + (col0&7);
            #pragma unroll
            for (int j = 0; j < 4; j++){
                int row = j*16 + c;
                uint2 hv = *(const uint2*)(A + row*128 + coff);
                float h0v[4] = { b2f((u16)(hv.x & 0xffffu)), b2f((u16)(hv.x >> 16)),
                                 b2f((u16)(hv.y & 0xffffu)), b2f((u16)(hv.y >> 16)) };
                f4v h3o;
                #pragma unroll
                for (int r = 0; r < 4; r++){
                    float xn = aIn[i][j][r] + (&bi.x)[r] + rrA[i][j][r]*(aHn[i][j][r] + (&bh.x)[r]);
                    float e2 = __builtin_amdgcn_exp2f(-2.f*L2E*fabsf(xn));
                    float th = (1.f - e2)*__builtin_amdgcn_rcpf(1.f + e2);
                    th = (xn >= 0.f) ? th : -th;
                    float zv = zzA[i][j][r];
                    h3o[r] = (1.f - zv)*th + zv*h0v[r];
                }
                uint2 o; o.x = pk2(h3o[0],h3o[1]); o.y = pk2(h3o[2],h3o[3]);
                *(uint2*)(B + row*128 + coff) = o;   // h3 bf16 -> B (for qs GEMM)
                __builtin_nontemporal_store(h3o, (f4v*)(out_h3 + (rowbase + row)*128 + col0));
            }
        }
    }
    BARX();   // h3 visible

    // ---- final linear (units 29,30) + qs stores ----
    {
        f32x4 qa[2][4];
        float4 lb0 = (col00 < 20) ? *(const float4*)(wsb + 1920 + col00) : (float4){0.f,0.f,0.f,0.f};
        float4 lb1 = (col01 < 20) ? *(const float4*)(wsb + 1920 + col01) : (float4){0.f,0.f,0.f,0.f};
        loadX(xf, B, 0, c, g);
        wgemmW<true>(g29, xf, qa);
        loadX(xf, B, 1, c, g);
        wgemmW<false>(g30, xf, qa);

        #pragma unroll
        for (int i = 0; i < 2; i++){
            int col0 = w*32 + i*16 + g*4;
            if (col0 < 20){
                float4 lb = i ? lb1 : lb0;
                #pragma unroll
                for (int j = 0; j < 4; j++){
                    int row = j*16 + c;
                    f4v o;
                    o.x = qa[i][j][0]+lb.x; o.y = qa[i][j][1]+lb.y;
                    o.z = qa[i][j][2]+lb.z; o.w = qa[i][j][3]+lb.w;
                    __builtin_nontemporal_store(o, (f4v*)(out_qs + (rowbase + row)*20 + col0));
                }
            }
        }
    }
}

extern "C" void kernel_launch(void* const* d_in, const int* in_sizes, int n_in,
                              void* d_out, int out_size, void* d_ws, size_t ws_size,
                              hipStream_t stream) {
    const float* x     = (const float*)d_in[0];
    const int*   mask  = (const int*)  d_in[1];
    const float* h0    = (const float*)d_in[2];
    const float* enc_w = (const float*)d_in[3];
    const float* enc_b = (const float*)d_in[4];
    const float* q1_w  = (const float*)d_in[5];  const float* q1_b = (const float*)d_in[6];
    const float* k1_w  = (const float*)d_in[7];  const float* k1_b = (const float*)d_in[8];
    const float* v1_w  = (const float*)d_in[9];  const float* v1_b = (const float*)d_in[10];
    const float* o1_w  = (const float*)d_in[11]; const float* o1_b = (const float*)d_in[12];
    const float* q2_w  = (const float*)d_in[13]; const float* q2_b = (const float*)d_in[14];
    const float* k2_w  = (const float*)d_in[15]; const float* k2_b = (const float*)d_in[16];
    const float* v2_w  = (const float*)d_in[17]; const float* v2_b = (const float*)d_in[18];
    const float* o2_w  = (const float*)d_in[19]; const float* o2_b = (const float*)d_in[20];
    const float* gwih  = (const float*)d_in[21]; const float* gwhh = (const float*)d_in[22];
    const float* gbih  = (const float*)d_in[23]; const float* gbhh = (const float*)d_in[24];
    const float* lin_w = (const float*)d_in[25]; const float* lin_b = (const float*)d_in[26];

    const int bs = in_sizes[0] / (64 * 64);           // 4096
    float* out_qs = (float*)d_out;
    float* out_h3 = out_qs + (size_t)bs * 64 * 20;
    u16* W16 = (u16*)d_ws;

    const int total = NUNITS*8192 + NBIAS;
    hipLaunchKernelGGL(convert_weights, dim3((total + 255) / 256), dim3(256), 0, stream,
                       enc_w, q1_w, k1_w, v1_w, o1_w, q2_w, k2_w, v2_w, o2_w,
                       gwih, gwhh, lin_w,
                       enc_b, q1_b, k1_b, v1_b, o1_b, q2_b, k2_b, v2_b, o2_b,
                       gbih, gbhh, lin_b, W16);
    hipLaunchKernelGGL(drgn_pipe, dim3(bs), dim3(256), 0, stream,
                       x, mask, h0, W16, out_qs, out_h3);
}